// Round 6
// baseline (550.196 us; speedup 1.0000x reference)
//
#include <hip/hip_runtime.h>
#include <hip/hip_bf16.h>
#include <hip/hip_cooperative_groups.h>

namespace cg = cooperative_groups;

#define NEG_SLOPE 0.2f

typedef unsigned int uint;
typedef unsigned short ushort;
typedef __attribute__((ext_vector_type(8))) short short8;
typedef __attribute__((ext_vector_type(4))) float floatx4;

static __device__ __forceinline__ ushort f2bf(float f) {
    uint u = __float_as_uint(f);
    uint r = (u + 0x7fffu + ((u >> 16) & 1u)) >> 16;  // RNE
    return (ushort)r;
}
static __device__ __forceinline__ float bf2f(uint s) {
    return __uint_as_float(s << 16);
}

// ---------------- fused CSR build (cooperative, 256 blocks) ----------------
// phases: zero deg -> histogram -> chunk scans -> (redundant) top scan ->
// final row-starts rs[n+1] + cursor -> fill csr_src.
__global__ __launch_bounds__(256) void csr_coop(
    const int* __restrict__ src, const int* __restrict__ dst,
    int* __restrict__ deg, int* __restrict__ rs, int* __restrict__ cursor,
    int* __restrict__ bsum, int* __restrict__ csr_src, int n, int E) {
    cg::grid_group grid = cg::this_grid();
    __shared__ int sh[256];
    int tid = threadIdx.x;
    int gsz = gridDim.x * blockDim.x;
    int gtid = blockIdx.x * blockDim.x + tid;
    // 1: zero degree counters
    for (int i = gtid; i < n; i += gsz) deg[i] = 0;
    grid.sync();
    // 2: histogram (fire-and-forget atomics, fully pipelined)
    for (int e = gtid; e < E; e += gsz) atomicAdd(&deg[dst[e]], 1);
    grid.sync();
    // 3: per-256-chunk inclusive scan; incl -> rs (temp), totals -> bsum
    int nchunks = (n + 255) >> 8;
    for (int c = blockIdx.x; c < nchunks; c += gridDim.x) {
        int i = c * 256 + tid;
        sh[tid] = (i < n) ? deg[i] : 0;
        __syncthreads();
        for (int off = 1; off < 256; off <<= 1) {
            int t = (tid >= off) ? sh[tid - off] : 0;
            __syncthreads();
            sh[tid] += t;
            __syncthreads();
        }
        if (i < n) rs[i] = sh[tid];
        if (tid == 255) bsum[c] = sh[255];
        __syncthreads();
    }
    grid.sync();
    // 4: every block redundantly computes exclusive top-scan of bsum in LDS
    {
        int own = (tid < nchunks) ? bsum[tid] : 0;
        sh[tid] = own;
        __syncthreads();
        for (int off = 1; off < 256; off <<= 1) {
            int t = (tid >= off) ? sh[tid - off] : 0;
            __syncthreads();
            sh[tid] += t;
            __syncthreads();
        }
        sh[tid] -= own;
        __syncthreads();
    }
    // 5: final rs (exclusive) + cursor; rs[n] = E
    for (int i = gtid; i < n; i += gsz) {
        int v = rs[i] - deg[i] + sh[i >> 8];
        rs[i] = v;
        cursor[i] = v;
    }
    if (gtid == 0) rs[n] = E;
    grid.sync();
    // 6: fill
    for (int e = gtid; e < E; e += gsz) {
        int d = dst[e];
        int pos = atomicAdd(&cursor[d], 1);
        csr_src[pos] = src[e];
    }
}

// ---------------- weight prep: transposes + folds --------------------------
__global__ __launch_bounds__(256) void prep_weights(
    const float* __restrict__ W1_src, const float* __restrict__ W2_src,
    const float* __restrict__ W1_dst, const float* __restrict__ a1_dst,
    const float* __restrict__ W2_dst, const float* __restrict__ a2_dst,
    ushort* __restrict__ W1t, ushort* __restrict__ W2t,
    float* __restrict__ wc1, float* __restrict__ wc2) {
    int i = blockIdx.x * blockDim.x + threadIdx.x;
    if (i < 32768) {
        int nc = i & 255, k = i >> 8;
        W1t[nc * 128 + k] = f2bf(W1_src[k * 256 + nc]);
    } else if (i < 32768 + 8192) {
        int i2 = i - 32768;
        int c = i2 & 31, k = i2 >> 5;
        W2t[c * 256 + k] = f2bf(W2_src[k * 32 + c]);
    } else if (i < 32768 + 8192 + 1024) {
        int i3 = i - 32768 - 8192;
        int k = i3 >> 3, h = i3 & 7;
        float s = 0.f;
#pragma unroll
        for (int c = 0; c < 32; ++c)
            s += W1_dst[k * 256 + h * 32 + c] * a1_dst[h * 32 + c];
        wc1[i3] = s;
    } else if (i < 32768 + 8192 + 1024 + 256) {
        int k = i - 32768 - 8192 - 1024;
        float s = 0.f;
#pragma unroll
        for (int c = 0; c < 32; ++c)
            s += W2_dst[k * 32 + c] * a2_dst[c];
        wc2[k] = s;
    }
}

// ---------------- GEMM1 via MFMA: head-major hs1h, as1h, ad1h --------------
// grid: M-tiles x 2 N-halves. block 256 = 4 waves, each 64x64 out.
// A staged from fp32 x with inline bf16 conversion (convert_x fused).
__global__ __launch_bounds__(256) void gemm1_mfma(
    const float* __restrict__ x, const ushort* __restrict__ W1t,
    const float* __restrict__ a_src, const float* __restrict__ wc1,
    ushort* __restrict__ hs1h, float* __restrict__ as1h,
    float* __restrict__ ad1h, int n) {
    __shared__ ushort At[128 * 128];   // 32 KB
    __shared__ ushort Out[128 * 128];  // 32 KB
    int mblk = blockIdx.x >> 1, nhalf = blockIdx.x & 1;
    int m0 = mblk * 128;
    int tid = threadIdx.x;
#pragma unroll
    for (int i = 0; i < 8; ++i) {
        int id = tid + i * 256;
        int m = id >> 4, c = id & 15;
        int gm = m0 + m;
        uint4 pk = {0, 0, 0, 0};
        if (gm < n) {
            const float4* xp = (const float4*)(x + (size_t)gm * 128 + c * 8);
            float4 v0 = xp[0], v1 = xp[1];
            pk.x = (uint)f2bf(v0.x) | ((uint)f2bf(v0.y) << 16);
            pk.y = (uint)f2bf(v0.z) | ((uint)f2bf(v0.w) << 16);
            pk.z = (uint)f2bf(v1.x) | ((uint)f2bf(v1.y) << 16);
            pk.w = (uint)f2bf(v1.z) | ((uint)f2bf(v1.w) << 16);
        }
        *(uint4*)(At + m * 128 + ((c ^ (m & 15)) * 8)) = pk;
    }
    __syncthreads();
    int wid = tid >> 6, lane = tid & 63;
    int q = lane >> 4, l16 = lane & 15;
    int wm = (wid >> 1) * 64;
    int wn = (wid & 1) * 64;
    int gn0 = nhalf * 128 + wn;
    floatx4 z = {0.f, 0.f, 0.f, 0.f};
    floatx4 acc[4][4];
#pragma unroll
    for (int mt = 0; mt < 4; ++mt)
#pragma unroll
        for (int nt = 0; nt < 4; ++nt) acc[mt][nt] = z;
#pragma unroll
    for (int s = 0; s < 4; ++s) {
        short8 af[4], bf[4];
#pragma unroll
        for (int mt = 0; mt < 4; ++mt) {
            int row = wm + mt * 16 + l16;
            int c = s * 4 + q;
            af[mt] = *(const short8*)(At + row * 128 + ((c ^ (row & 15)) * 8));
        }
#pragma unroll
        for (int nt = 0; nt < 4; ++nt) {
            int col = gn0 + nt * 16 + l16;
            bf[nt] = *(const short8*)(W1t + col * 128 + s * 32 + q * 8);
        }
#pragma unroll
        for (int mt = 0; mt < 4; ++mt)
#pragma unroll
            for (int nt = 0; nt < 4; ++nt)
                acc[mt][nt] = __builtin_amdgcn_mfma_f32_16x16x32_bf16(
                    af[mt], bf[nt], acc[mt][nt], 0, 0, 0);
    }
#pragma unroll
    for (int mt = 0; mt < 4; ++mt)
#pragma unroll
        for (int nt = 0; nt < 4; ++nt) {
            floatx4 a = acc[mt][nt];
            int colL = wn + nt * 16 + l16;
#pragma unroll
            for (int r = 0; r < 4; ++r) {
                int rowL = wm + mt * 16 + q * 4 + r;
                Out[rowL * 128 + colL] = f2bf(a[r]);
            }
        }
    __syncthreads();
    // hs1h head-major: 128 m x 4 local heads x 4 chunks of 16B
#pragma unroll
    for (int i = 0; i < 8; ++i) {
        int id = tid + i * 256;
        int c4 = id & 3, m = (id >> 2) & 127, hl = id >> 9;
        int gm = m0 + m;
        if (gm < n) {
            uint4 v = *(uint4*)(Out + m * 128 + hl * 32 + c4 * 8);
            int h = nhalf * 4 + hl;
            *(uint4*)(hs1h + ((size_t)h * n + gm) * 32 + c4 * 8) = v;
        }
    }
    // alpha_s head-major: 128 m x 4 local heads
#pragma unroll
    for (int i = 0; i < 2; ++i) {
        int id = tid + i * 256;
        int m = id & 127, hl = id >> 7;
        int gm = m0 + m;
        if (gm < n) {
            int h = nhalf * 4 + hl;
            const ushort* row = Out + m * 128 + hl * 32;
            const float* av = a_src + h * 32;
            float s = 0.f;
#pragma unroll
            for (int c = 0; c < 32; ++c) s += bf2f(row[c]) * av[c];
            as1h[(size_t)h * n + gm] = s;
        }
    }
    // alpha_d head-major (only nhalf==0 blocks): 128 m x 8 heads
    if (nhalf == 0) {
#pragma unroll
        for (int i = 0; i < 4; ++i) {
            int id = tid + i * 256;
            int m = id & 127, h = id >> 7;
            int gm = m0 + m;
            if (gm < n) {
                float s = 0.f;
                for (int c = 0; c < 16; ++c) {
                    const ushort* p = At + m * 128 + ((c ^ (m & 15)) * 8);
#pragma unroll
                    for (int jj = 0; jj < 8; ++jj)
                        s += bf2f(p[jj]) * wc1[(c * 8 + jj) * 8 + h];
                }
                ad1h[(size_t)h * n + gm] = s;
            }
        }
    }
}

// ---------------- gather layer 1: single-head slice, XCD-affine ------------
// block = 4 waves = 4 nodes, head = blockIdx & 7 (3.2 MB slice per XCD L2).
// wave: 16 edge slots x 4 lanes; lane loads uint4 (8 bf16 ch) -> same
// per-edge issue count as the full-row variant, 1/4 the resident bytes.
__global__ __launch_bounds__(256) void gather1(
    const int* __restrict__ csr_src, const int* __restrict__ rs,
    const ushort* __restrict__ hs1h, const float* __restrict__ as1h,
    const float* __restrict__ ad1h, const float* __restrict__ b1,
    ushort* __restrict__ h1h, int n) {
    int h = blockIdx.x & 7;
    int wid = threadIdx.x >> 6;
    int node = (blockIdx.x >> 3) * 4 + wid;
    if (node >= n) return;
    int lane = threadIdx.x & 63;
    int g = lane >> 2, p = lane & 3;
    const ushort* tab = hs1h + (size_t)h * n * 32;
    const float* asv = as1h + (size_t)h * n;
    float ad_v = ad1h[(size_t)h * n + node];
    int start = rs[node], cnt = rs[node + 1] - start;
    float acc0 = 0.f, acc1 = 0.f, acc2 = 0.f, acc3 = 0.f;
    float acc4 = 0.f, acc5 = 0.f, acc6 = 0.f, acc7 = 0.f;
    float dacc = 0.f;
    for (int i = g; i < cnt; i += 16) {
        int s = csr_src[start + i];
        float t = asv[s] + ad_v;
        t = (t >= 0.f) ? t : NEG_SLOPE * t;
        float w = __expf(t);
        uint4 v = *(const uint4*)(tab + (size_t)s * 32 + p * 8);
        acc0 += bf2f(v.x & 0xffffu) * w;
        acc1 += bf2f(v.x >> 16) * w;
        acc2 += bf2f(v.y & 0xffffu) * w;
        acc3 += bf2f(v.y >> 16) * w;
        acc4 += bf2f(v.z & 0xffffu) * w;
        acc5 += bf2f(v.z >> 16) * w;
        acc6 += bf2f(v.w & 0xffffu) * w;
        acc7 += bf2f(v.w >> 16) * w;
        dacc += w;
    }
#pragma unroll
    for (int m = 4; m <= 32; m <<= 1) {
        acc0 += __shfl_xor(acc0, m, 64);
        acc1 += __shfl_xor(acc1, m, 64);
        acc2 += __shfl_xor(acc2, m, 64);
        acc3 += __shfl_xor(acc3, m, 64);
        acc4 += __shfl_xor(acc4, m, 64);
        acc5 += __shfl_xor(acc5, m, 64);
        acc6 += __shfl_xor(acc6, m, 64);
        acc7 += __shfl_xor(acc7, m, 64);
        dacc += __shfl_xor(dacc, m, 64);
    }
    if (g == 0) {
        float inv = 1.f / (dacc + 1e-16f);
        const float* bp = b1 + h * 32 + p * 8;
        float o0 = fmaxf(fmaf(acc0, inv, bp[0]), 0.f);
        float o1 = fmaxf(fmaf(acc1, inv, bp[1]), 0.f);
        float o2 = fmaxf(fmaf(acc2, inv, bp[2]), 0.f);
        float o3 = fmaxf(fmaf(acc3, inv, bp[3]), 0.f);
        float o4 = fmaxf(fmaf(acc4, inv, bp[4]), 0.f);
        float o5 = fmaxf(fmaf(acc5, inv, bp[5]), 0.f);
        float o6 = fmaxf(fmaf(acc6, inv, bp[6]), 0.f);
        float o7 = fmaxf(fmaf(acc7, inv, bp[7]), 0.f);
        uint4 pk;
        pk.x = (uint)f2bf(o0) | ((uint)f2bf(o1) << 16);
        pk.y = (uint)f2bf(o2) | ((uint)f2bf(o3) << 16);
        pk.z = (uint)f2bf(o4) | ((uint)f2bf(o5) << 16);
        pk.w = (uint)f2bf(o6) | ((uint)f2bf(o7) << 16);
        *(uint4*)(h1h + ((size_t)h * n + node) * 32 + p * 8) = pk;
    }
}

// ---------------- GEMM2 via MFMA: hs2b = bf16(h1 @ W2_src) -----------------
// grid ceil(n/128). block 256 = 4 waves, each 32x32 out. A from head-major h1h.
__global__ __launch_bounds__(256) void gemm2_mfma(
    const ushort* __restrict__ h1h, const ushort* __restrict__ W2t,
    const float* __restrict__ a2_src, const float* __restrict__ wc2,
    ushort* __restrict__ hs2b, float* __restrict__ as2,
    float* __restrict__ ad2, int n) {
    __shared__ ushort At[128 * 256];  // 64 KB
    __shared__ ushort Out[128 * 32];  // 8 KB
    int m0 = blockIdx.x * 128;
    int tid = threadIdx.x;
#pragma unroll
    for (int i = 0; i < 16; ++i) {
        int id = tid + i * 256;
        int c4 = id & 3, m = (id >> 2) & 127, hl = id >> 9;
        int gm = m0 + m;
        uint4 v = {0, 0, 0, 0};
        if (gm < n) v = *(const uint4*)(h1h + ((size_t)hl * n + gm) * 32 + c4 * 8);
        int c = hl * 4 + c4;
        *(uint4*)(At + m * 256 + ((c ^ (m & 15)) * 8)) = v;
    }
    __syncthreads();
    int wid = tid >> 6, lane = tid & 63;
    int q = lane >> 4, l16 = lane & 15;
    int wm = wid * 32;
    floatx4 z = {0.f, 0.f, 0.f, 0.f};
    floatx4 acc[2][2] = {{z, z}, {z, z}};
#pragma unroll
    for (int s = 0; s < 8; ++s) {
        short8 af[2], bf[2];
#pragma unroll
        for (int mt = 0; mt < 2; ++mt) {
            int row = wm + mt * 16 + l16;
            int c = s * 4 + q;
            af[mt] = *(const short8*)(At + row * 256 + ((c ^ (row & 15)) * 8));
        }
#pragma unroll
        for (int nt = 0; nt < 2; ++nt) {
            int col = nt * 16 + l16;
            bf[nt] = *(const short8*)(W2t + col * 256 + s * 32 + q * 8);
        }
#pragma unroll
        for (int mt = 0; mt < 2; ++mt)
#pragma unroll
            for (int nt = 0; nt < 2; ++nt)
                acc[mt][nt] = __builtin_amdgcn_mfma_f32_16x16x32_bf16(
                    af[mt], bf[nt], acc[mt][nt], 0, 0, 0);
    }
#pragma unroll
    for (int mt = 0; mt < 2; ++mt)
#pragma unroll
        for (int nt = 0; nt < 2; ++nt) {
            floatx4 a = acc[mt][nt];
            int colL = nt * 16 + l16;
#pragma unroll
            for (int r = 0; r < 4; ++r) {
                int rowL = wm + mt * 16 + q * 4 + r;
                Out[rowL * 32 + colL] = f2bf(a[r]);
            }
        }
    __syncthreads();
#pragma unroll
    for (int i = 0; i < 2; ++i) {
        int id = tid + i * 256;
        int c4 = id & 3, m = id >> 2;
        int gm = m0 + m;
        if (gm < n)
            *(uint4*)(hs2b + (size_t)gm * 32 + c4 * 8) =
                *(uint4*)(Out + m * 32 + c4 * 8);
    }
    if (tid < 128) {
        int gm = m0 + tid;
        if (gm < n) {
            float s = 0.f;
#pragma unroll
            for (int c2 = 0; c2 < 32; ++c2)
                s += bf2f(Out[tid * 32 + c2]) * a2_src[c2];
            as2[gm] = s;
        }
    } else {
        int m = tid - 128, gm = m0 + m;
        if (gm < n) {
            float s = 0.f;
            for (int c = 0; c < 32; ++c) {
                const ushort* p = At + m * 256 + ((c ^ (m & 15)) * 8);
#pragma unroll
                for (int jj = 0; jj < 8; ++jj)
                    s += bf2f(p[jj]) * wc2[c * 8 + jj];
            }
            ad2[gm] = s;
        }
    }
}

// ---------------- gather layer 2 (heads=1, 3.2 MB table) -------------------
__global__ __launch_bounds__(256) void gather2(
    const int* __restrict__ csr_src, const int* __restrict__ rs,
    const ushort* __restrict__ hs2b, const float* __restrict__ as2,
    const float* __restrict__ ad2, const float* __restrict__ b2,
    float* __restrict__ out, int n) {
    int gid = blockIdx.x * blockDim.x + threadIdx.x;
    int node = gid >> 6;
    int lane = threadIdx.x & 63;
    if (node >= n) return;
    int j = lane >> 4, l = lane & 15;
    float ad_v = ad2[node];
    int start = rs[node], cnt = rs[node + 1] - start;
    float accx = 0.f, accy = 0.f, dacc = 0.f;
    for (int i = j; i < cnt; i += 4) {
        int s = csr_src[start + i];
        float t = as2[s] + ad_v;
        t = (t >= 0.f) ? t : NEG_SLOPE * t;
        float w = __expf(t);
        uint v = *(const uint*)(hs2b + (size_t)s * 32 + l * 2);
        accx += bf2f(v & 0xffffu) * w;
        accy += bf2f(v >> 16) * w;
        dacc += w;
    }
    accx += __shfl_xor(accx, 32, 64);
    accy += __shfl_xor(accy, 32, 64);
    dacc += __shfl_xor(dacc, 32, 64);
    accx += __shfl_xor(accx, 16, 64);
    accy += __shfl_xor(accy, 16, 64);
    dacc += __shfl_xor(dacc, 16, 64);
    if (lane < 16) {
        float inv = 1.f / (dacc + 1e-16f);
        float2 bv = ((const float2*)b2)[l];
        float2 o;
        o.x = fmaf(accx, inv, bv.x);
        o.y = fmaf(accy, inv, bv.y);
        *(float2*)(out + (size_t)node * 32 + l * 2) = o;
    }
}

extern "C" void kernel_launch(void* const* d_in, const int* in_sizes, int n_in,
                              void* d_out, int out_size, void* d_ws, size_t ws_size,
                              hipStream_t stream) {
    const float* x      = (const float*)d_in[0];
    const int*   eidx   = (const int*)d_in[1];
    const float* W1_src = (const float*)d_in[2];
    const float* W1_dst = (const float*)d_in[3];
    const float* a1_src = (const float*)d_in[4];
    const float* a1_dst = (const float*)d_in[5];
    const float* b1     = (const float*)d_in[6];
    const float* W2_src = (const float*)d_in[7];
    const float* W2_dst = (const float*)d_in[8];
    const float* a2_src = (const float*)d_in[9];
    const float* a2_dst = (const float*)d_in[10];
    const float* b2     = (const float*)d_in[11];

    int n = in_sizes[0] / 128;    // 50000
    int E = in_sizes[1] / 2;      // 800000
    const int* srcp = eidx;
    const int* dstp = eidx + E;

    char* ws = (char*)d_ws;
    size_t o = 0;
    auto alloc = [&](size_t bytes) {
        void* p = ws + o;
        o += (bytes + 255) & ~(size_t)255;
        return p;
    };
    ushort* W1t  = (ushort*)alloc(256 * 128 * 2);
    ushort* W2t  = (ushort*)alloc(32 * 256 * 2);
    ushort* hs1h = (ushort*)alloc((size_t)8 * n * 32 * 2);
    ushort* h1h  = (ushort*)alloc((size_t)8 * n * 32 * 2);
    ushort* hs2b = (ushort*)alloc((size_t)n * 32 * 2);
    float* as1h = (float*)alloc((size_t)8 * n * 4);
    float* ad1h = (float*)alloc((size_t)8 * n * 4);
    float* as2  = (float*)alloc((size_t)n * 4);
    float* ad2  = (float*)alloc((size_t)n * 4);
    float* wc1  = (float*)alloc(1024 * 4);
    float* wc2  = (float*)alloc(256 * 4);
    int* deg     = (int*)alloc((size_t)n * 4);
    int* rs      = (int*)alloc(((size_t)n + 1) * 4);
    int* cursor  = (int*)alloc((size_t)n * 4);
    int* bsum    = (int*)alloc(256 * 4);
    int* csr_src = (int*)alloc((size_t)E * 4);

    // fused CSR build (cooperative: 256 blocks co-resident, grid.sync phases)
    {
        void* args[] = {(void*)&srcp, (void*)&dstp, (void*)&deg, (void*)&rs,
                        (void*)&cursor, (void*)&bsum, (void*)&csr_src,
                        (void*)&n, (void*)&E};
        hipLaunchCooperativeKernel((void*)csr_coop, dim3(256), dim3(256),
                                   args, 0, stream);
    }

    prep_weights<<<(32768 + 8192 + 1024 + 256 + 255) / 256, 256, 0, stream>>>(
        W1_src, W2_src, W1_dst, a1_dst, W2_dst, a2_dst, W1t, W2t, wc1, wc2);

    // layer 1
    gemm1_mfma<<<((n + 127) / 128) * 2, 256, 0, stream>>>(
        x, W1t, a1_src, wc1, hs1h, as1h, ad1h, n);
    gather1<<<((n + 3) / 4) * 8, 256, 0, stream>>>(
        csr_src, rs, hs1h, as1h, ad1h, b1, h1h, n);

    // layer 2
    gemm2_mfma<<<(n + 127) / 128, 256, 0, stream>>>(
        h1h, W2t, a2_src, wc2, hs2b, as2, ad2, n);
    gather2<<<(n + 3) / 4, 256, 0, stream>>>(
        csr_src, rs, hs2b, as2, ad2, b2, (float*)d_out, n);
}

// Round 7
// 326.417 us; speedup vs baseline: 1.6856x; 1.6856x over previous
//
#include <hip/hip_runtime.h>
#include <hip/hip_bf16.h>

#define NEG_SLOPE 0.2f

typedef unsigned int uint;
typedef unsigned short ushort;
typedef __attribute__((ext_vector_type(8))) short short8;
typedef __attribute__((ext_vector_type(4))) float floatx4;

static __device__ __forceinline__ ushort f2bf(float f) {
    uint u = __float_as_uint(f);
    uint r = (u + 0x7fffu + ((u >> 16) & 1u)) >> 16;  // RNE
    return (ushort)r;
}
static __device__ __forceinline__ float bf2f(uint s) {
    return __uint_as_float(s << 16);
}

// ---------------- CSR build (separate wide-grid kernels) -------------------
__global__ __launch_bounds__(256) void hist_kernel(
    const int* __restrict__ dst, int* __restrict__ deg, int E) {
    int e = blockIdx.x * blockDim.x + threadIdx.x;
    if (e < E) atomicAdd(&deg[dst[e]], 1);
}

// per-256-chunk inclusive scan; incl -> rs (temp), chunk totals -> bsum
__global__ __launch_bounds__(256) void scan_block(
    const int* __restrict__ deg, int* __restrict__ rs,
    int* __restrict__ bsum, int n) {
    __shared__ int sh[256];
    int tid = threadIdx.x;
    int i = blockIdx.x * 256 + tid;
    sh[tid] = (i < n) ? deg[i] : 0;
    __syncthreads();
    for (int off = 1; off < 256; off <<= 1) {
        int t = (tid >= off) ? sh[tid - off] : 0;
        __syncthreads();
        sh[tid] += t;
        __syncthreads();
    }
    if (i < n) rs[i] = sh[tid];
    if (tid == 255) bsum[blockIdx.x] = sh[255];
}

// each block redundantly top-scans bsum in LDS, then finalizes its chunk:
// rs[i] = exclusive row start; cursor[i] = same; rs[n] = E.
__global__ __launch_bounds__(256) void rs_kernel(
    const int* __restrict__ deg, const int* __restrict__ bsum,
    int* __restrict__ rs, int* __restrict__ cursor, int n, int E, int nb) {
    __shared__ int sh[256];
    int tid = threadIdx.x;
    int own = (tid < nb) ? bsum[tid] : 0;
    sh[tid] = own;
    __syncthreads();
    for (int off = 1; off < 256; off <<= 1) {
        int t = (tid >= off) ? sh[tid - off] : 0;
        __syncthreads();
        sh[tid] += t;
        __syncthreads();
    }
    int boff = sh[blockIdx.x] - ((blockIdx.x < nb) ? bsum[blockIdx.x] : 0);
    __syncthreads();
    int i = blockIdx.x * 256 + tid;
    if (i < n) {
        int v = rs[i] - deg[i] + boff;
        rs[i] = v;
        cursor[i] = v;
    }
    if (i == 0) rs[n] = E;
}

__global__ __launch_bounds__(256) void fill_kernel(
    const int* __restrict__ src, const int* __restrict__ dst,
    int* __restrict__ cursor, int* __restrict__ csr_src, int E) {
    int e = blockIdx.x * blockDim.x + threadIdx.x;
    if (e >= E) return;
    int d = dst[e];
    int pos = atomicAdd(&cursor[d], 1);
    csr_src[pos] = src[e];
}

// ---------------- weight prep: transposes + folds --------------------------
__global__ __launch_bounds__(256) void prep_weights(
    const float* __restrict__ W1_src, const float* __restrict__ W2_src,
    const float* __restrict__ W1_dst, const float* __restrict__ a1_dst,
    const float* __restrict__ W2_dst, const float* __restrict__ a2_dst,
    ushort* __restrict__ W1t, ushort* __restrict__ W2t,
    float* __restrict__ wc1, float* __restrict__ wc2) {
    int i = blockIdx.x * blockDim.x + threadIdx.x;
    if (i < 32768) {
        int nc = i & 255, k = i >> 8;
        W1t[nc * 128 + k] = f2bf(W1_src[k * 256 + nc]);
    } else if (i < 32768 + 8192) {
        int i2 = i - 32768;
        int c = i2 & 31, k = i2 >> 5;
        W2t[c * 256 + k] = f2bf(W2_src[k * 32 + c]);
    } else if (i < 32768 + 8192 + 1024) {
        int i3 = i - 32768 - 8192;
        int k = i3 >> 3, h = i3 & 7;
        float s = 0.f;
#pragma unroll
        for (int c = 0; c < 32; ++c)
            s += W1_dst[k * 256 + h * 32 + c] * a1_dst[h * 32 + c];
        wc1[i3] = s;
    } else if (i < 32768 + 8192 + 1024 + 256) {
        int k = i - 32768 - 8192 - 1024;
        float s = 0.f;
#pragma unroll
        for (int c = 0; c < 32; ++c)
            s += W2_dst[k * 32 + c] * a2_dst[c];
        wc2[k] = s;
    }
}

// ---------------- GEMM1 via MFMA: hs1b = bf16(x @ W1_src) node-major -------
// grid: M-tiles x 2 N-halves. block 256 = 4 waves, each 64x64 out.
// A staged from fp32 x with inline bf16 conversion.
__global__ __launch_bounds__(256) void gemm1_mfma(
    const float* __restrict__ x, const ushort* __restrict__ W1t,
    const float* __restrict__ a_src, const float* __restrict__ wc1,
    ushort* __restrict__ hs1b, float* __restrict__ as1,
    float* __restrict__ ad1, int n) {
    __shared__ ushort At[128 * 128];   // 32 KB
    __shared__ ushort Out[128 * 128];  // 32 KB
    int mblk = blockIdx.x >> 1, nhalf = blockIdx.x & 1;
    int m0 = mblk * 128;
    int tid = threadIdx.x;
#pragma unroll
    for (int i = 0; i < 8; ++i) {
        int id = tid + i * 256;
        int m = id >> 4, c = id & 15;
        int gm = m0 + m;
        uint4 pk = {0, 0, 0, 0};
        if (gm < n) {
            const float4* xp = (const float4*)(x + (size_t)gm * 128 + c * 8);
            float4 v0 = xp[0], v1 = xp[1];
            pk.x = (uint)f2bf(v0.x) | ((uint)f2bf(v0.y) << 16);
            pk.y = (uint)f2bf(v0.z) | ((uint)f2bf(v0.w) << 16);
            pk.z = (uint)f2bf(v1.x) | ((uint)f2bf(v1.y) << 16);
            pk.w = (uint)f2bf(v1.z) | ((uint)f2bf(v1.w) << 16);
        }
        *(uint4*)(At + m * 128 + ((c ^ (m & 15)) * 8)) = pk;
    }
    __syncthreads();
    int wid = tid >> 6, lane = tid & 63;
    int q = lane >> 4, l16 = lane & 15;
    int wm = (wid >> 1) * 64;
    int wn = (wid & 1) * 64;
    int gn0 = nhalf * 128 + wn;
    floatx4 z = {0.f, 0.f, 0.f, 0.f};
    floatx4 acc[4][4];
#pragma unroll
    for (int mt = 0; mt < 4; ++mt)
#pragma unroll
        for (int nt = 0; nt < 4; ++nt) acc[mt][nt] = z;
#pragma unroll
    for (int s = 0; s < 4; ++s) {
        short8 af[4], bf[4];
#pragma unroll
        for (int mt = 0; mt < 4; ++mt) {
            int row = wm + mt * 16 + l16;
            int c = s * 4 + q;
            af[mt] = *(const short8*)(At + row * 128 + ((c ^ (row & 15)) * 8));
        }
#pragma unroll
        for (int nt = 0; nt < 4; ++nt) {
            int col = gn0 + nt * 16 + l16;
            bf[nt] = *(const short8*)(W1t + col * 128 + s * 32 + q * 8);
        }
#pragma unroll
        for (int mt = 0; mt < 4; ++mt)
#pragma unroll
            for (int nt = 0; nt < 4; ++nt)
                acc[mt][nt] = __builtin_amdgcn_mfma_f32_16x16x32_bf16(
                    af[mt], bf[nt], acc[mt][nt], 0, 0, 0);
    }
#pragma unroll
    for (int mt = 0; mt < 4; ++mt)
#pragma unroll
        for (int nt = 0; nt < 4; ++nt) {
            floatx4 a = acc[mt][nt];
            int colL = wn + nt * 16 + l16;
#pragma unroll
            for (int r = 0; r < 4; ++r) {
                int rowL = wm + mt * 16 + q * 4 + r;
                Out[rowL * 128 + colL] = f2bf(a[r]);
            }
        }
    __syncthreads();
    // write hs1b node-major: 128 m x 16 uint4 chunks
#pragma unroll
    for (int i = 0; i < 8; ++i) {
        int id = tid + i * 256;
        int m = id >> 4, c8 = id & 15;
        int gm = m0 + m;
        if (gm < n) {
            uint4 v = *(uint4*)(Out + m * 128 + c8 * 8);
            *(uint4*)(hs1b + (size_t)gm * 256 + nhalf * 128 + c8 * 8) = v;
        }
    }
    // alpha_s: 128 m x 4 local heads
#pragma unroll
    for (int i = 0; i < 2; ++i) {
        int id = tid + i * 256;
        int m = id & 127, hl = id >> 7;
        int gm = m0 + m;
        if (gm < n) {
            int h = nhalf * 4 + hl;
            const ushort* row = Out + m * 128 + hl * 32;
            const float* av = a_src + h * 32;
            float s = 0.f;
#pragma unroll
            for (int c = 0; c < 32; ++c) s += bf2f(row[c]) * av[c];
            as1[(size_t)gm * 8 + h] = s;
        }
    }
    // alpha_d (only nhalf==0): 128 m x 8 heads
    if (nhalf == 0) {
#pragma unroll
        for (int i = 0; i < 4; ++i) {
            int id = tid + i * 256;
            int m = id & 127, h = id >> 7;
            int gm = m0 + m;
            if (gm < n) {
                float s = 0.f;
                for (int c = 0; c < 16; ++c) {
                    const ushort* p = At + m * 128 + ((c ^ (m & 15)) * 8);
#pragma unroll
                    for (int jj = 0; jj < 8; ++jj)
                        s += bf2f(p[jj]) * wc1[(c * 8 + jj) * 8 + h];
                }
                ad1[(size_t)gm * 8 + h] = s;
            }
        }
    }
}

// ---------------- gather layer 1: wave = node, all 8 heads -----------------
// half-wave lane l (0..31) owns channels l*8..l*8+7 (uint4), head = l>>2.
// j = lane>>5 selects edge parity; loop unrolled x2 -> 4 edges in flight.
__global__ __launch_bounds__(256) void gather1(
    const int* __restrict__ csr_src, const int* __restrict__ rs,
    const ushort* __restrict__ hs1b, const float* __restrict__ as1,
    const float* __restrict__ ad1, const float* __restrict__ b1,
    ushort* __restrict__ h1b, int n) {
    int gid = blockIdx.x * blockDim.x + threadIdx.x;
    int node = gid >> 6;
    int lane = threadIdx.x & 63;
    if (node >= n) return;
    int j = lane >> 5, l = lane & 31;
    int h = l >> 2;
    float ad_v = ad1[node * 8 + h];
    int start = rs[node], cnt = rs[node + 1] - start;
    float acc0 = 0.f, acc1 = 0.f, acc2 = 0.f, acc3 = 0.f;
    float acc4 = 0.f, acc5 = 0.f, acc6 = 0.f, acc7 = 0.f;
    float dacc = 0.f;
    int i = j;
    for (; i + 2 < cnt; i += 4) {
        int sA = csr_src[start + i];
        int sB = csr_src[start + i + 2];
        float tA = as1[sA * 8 + h] + ad_v;
        float tB = as1[sB * 8 + h] + ad_v;
        uint4 vA = *(const uint4*)(hs1b + (size_t)sA * 256 + l * 8);
        uint4 vB = *(const uint4*)(hs1b + (size_t)sB * 256 + l * 8);
        tA = (tA >= 0.f) ? tA : NEG_SLOPE * tA;
        tB = (tB >= 0.f) ? tB : NEG_SLOPE * tB;
        float wA = __expf(tA);
        float wB = __expf(tB);
        acc0 += bf2f(vA.x & 0xffffu) * wA + bf2f(vB.x & 0xffffu) * wB;
        acc1 += bf2f(vA.x >> 16) * wA + bf2f(vB.x >> 16) * wB;
        acc2 += bf2f(vA.y & 0xffffu) * wA + bf2f(vB.y & 0xffffu) * wB;
        acc3 += bf2f(vA.y >> 16) * wA + bf2f(vB.y >> 16) * wB;
        acc4 += bf2f(vA.z & 0xffffu) * wA + bf2f(vB.z & 0xffffu) * wB;
        acc5 += bf2f(vA.z >> 16) * wA + bf2f(vB.z >> 16) * wB;
        acc6 += bf2f(vA.w & 0xffffu) * wA + bf2f(vB.w & 0xffffu) * wB;
        acc7 += bf2f(vA.w >> 16) * wA + bf2f(vB.w >> 16) * wB;
        dacc += wA + wB;
    }
    for (; i < cnt; i += 2) {
        int s = csr_src[start + i];
        float t = as1[s * 8 + h] + ad_v;
        uint4 v = *(const uint4*)(hs1b + (size_t)s * 256 + l * 8);
        t = (t >= 0.f) ? t : NEG_SLOPE * t;
        float w = __expf(t);
        acc0 += bf2f(v.x & 0xffffu) * w;
        acc1 += bf2f(v.x >> 16) * w;
        acc2 += bf2f(v.y & 0xffffu) * w;
        acc3 += bf2f(v.y >> 16) * w;
        acc4 += bf2f(v.z & 0xffffu) * w;
        acc5 += bf2f(v.z >> 16) * w;
        acc6 += bf2f(v.w & 0xffffu) * w;
        acc7 += bf2f(v.w >> 16) * w;
        dacc += w;
    }
    acc0 += __shfl_xor(acc0, 32, 64);
    acc1 += __shfl_xor(acc1, 32, 64);
    acc2 += __shfl_xor(acc2, 32, 64);
    acc3 += __shfl_xor(acc3, 32, 64);
    acc4 += __shfl_xor(acc4, 32, 64);
    acc5 += __shfl_xor(acc5, 32, 64);
    acc6 += __shfl_xor(acc6, 32, 64);
    acc7 += __shfl_xor(acc7, 32, 64);
    dacc += __shfl_xor(dacc, 32, 64);
    if (j == 0) {
        float inv = 1.f / (dacc + 1e-16f);
        float4 b0 = ((const float4*)b1)[l * 2];
        float4 b4 = ((const float4*)b1)[l * 2 + 1];
        float o0 = fmaxf(fmaf(acc0, inv, b0.x), 0.f);
        float o1 = fmaxf(fmaf(acc1, inv, b0.y), 0.f);
        float o2 = fmaxf(fmaf(acc2, inv, b0.z), 0.f);
        float o3 = fmaxf(fmaf(acc3, inv, b0.w), 0.f);
        float o4 = fmaxf(fmaf(acc4, inv, b4.x), 0.f);
        float o5 = fmaxf(fmaf(acc5, inv, b4.y), 0.f);
        float o6 = fmaxf(fmaf(acc6, inv, b4.z), 0.f);
        float o7 = fmaxf(fmaf(acc7, inv, b4.w), 0.f);
        uint4 pk;
        pk.x = (uint)f2bf(o0) | ((uint)f2bf(o1) << 16);
        pk.y = (uint)f2bf(o2) | ((uint)f2bf(o3) << 16);
        pk.z = (uint)f2bf(o4) | ((uint)f2bf(o5) << 16);
        pk.w = (uint)f2bf(o6) | ((uint)f2bf(o7) << 16);
        *(uint4*)(h1b + (size_t)node * 256 + l * 8) = pk;
    }
}

// ---------------- GEMM2 via MFMA: hs2b = bf16(h1 @ W2_src) -----------------
__global__ __launch_bounds__(256) void gemm2_mfma(
    const ushort* __restrict__ h1b, const ushort* __restrict__ W2t,
    const float* __restrict__ a2_src, const float* __restrict__ wc2,
    ushort* __restrict__ hs2b, float* __restrict__ as2,
    float* __restrict__ ad2, int n) {
    __shared__ ushort At[128 * 256];  // 64 KB
    __shared__ ushort Out[128 * 32];  // 8 KB
    int m0 = blockIdx.x * 128;
    int tid = threadIdx.x;
#pragma unroll
    for (int i = 0; i < 16; ++i) {
        int id = tid + i * 256;
        int m = id >> 5, c = id & 31;
        int gm = m0 + m;
        uint4 v = {0, 0, 0, 0};
        if (gm < n) v = *(const uint4*)(h1b + (size_t)gm * 256 + c * 8);
        *(uint4*)(At + m * 256 + ((c ^ (m & 15)) * 8)) = v;
    }
    __syncthreads();
    int wid = tid >> 6, lane = tid & 63;
    int q = lane >> 4, l16 = lane & 15;
    int wm = wid * 32;
    floatx4 z = {0.f, 0.f, 0.f, 0.f};
    floatx4 acc[2][2] = {{z, z}, {z, z}};
#pragma unroll
    for (int s = 0; s < 8; ++s) {
        short8 af[2], bf[2];
#pragma unroll
        for (int mt = 0; mt < 2; ++mt) {
            int row = wm + mt * 16 + l16;
            int c = s * 4 + q;
            af[mt] = *(const short8*)(At + row * 256 + ((c ^ (row & 15)) * 8));
        }
#pragma unroll
        for (int nt = 0; nt < 2; ++nt) {
            int col = nt * 16 + l16;
            bf[nt] = *(const short8*)(W2t + col * 256 + s * 32 + q * 8);
        }
#pragma unroll
        for (int mt = 0; mt < 2; ++mt)
#pragma unroll
            for (int nt = 0; nt < 2; ++nt)
                acc[mt][nt] = __builtin_amdgcn_mfma_f32_16x16x32_bf16(
                    af[mt], bf[nt], acc[mt][nt], 0, 0, 0);
    }
#pragma unroll
    for (int mt = 0; mt < 2; ++mt)
#pragma unroll
        for (int nt = 0; nt < 2; ++nt) {
            floatx4 a = acc[mt][nt];
            int colL = nt * 16 + l16;
#pragma unroll
            for (int r = 0; r < 4; ++r) {
                int rowL = wm + mt * 16 + q * 4 + r;
                Out[rowL * 32 + colL] = f2bf(a[r]);
            }
        }
    __syncthreads();
#pragma unroll
    for (int i = 0; i < 2; ++i) {
        int id = tid + i * 256;
        int c4 = id & 3, m = id >> 2;
        int gm = m0 + m;
        if (gm < n)
            *(uint4*)(hs2b + (size_t)gm * 32 + c4 * 8) =
                *(uint4*)(Out + m * 32 + c4 * 8);
    }
    if (tid < 128) {
        int gm = m0 + tid;
        if (gm < n) {
            float s = 0.f;
#pragma unroll
            for (int c2 = 0; c2 < 32; ++c2)
                s += bf2f(Out[tid * 32 + c2]) * a2_src[c2];
            as2[gm] = s;
        }
    } else {
        int m = tid - 128, gm = m0 + m;
        if (gm < n) {
            float s = 0.f;
            for (int c = 0; c < 32; ++c) {
                const ushort* p = At + m * 256 + ((c ^ (m & 15)) * 8);
#pragma unroll
                for (int jj = 0; jj < 8; ++jj)
                    s += bf2f(p[jj]) * wc2[c * 8 + jj];
            }
            ad2[gm] = s;
        }
    }
}

// ---------------- gather layer 2 (heads=1): 8 lanes/edge x 8 slots ---------
// lane l (0..7) owns channels l*4..l*4+3 (uint2 of bf16); group g = lane>>3
// is the edge slot; reduction across groups via shfl_xor 8/16/32.
__global__ __launch_bounds__(256) void gather2(
    const int* __restrict__ csr_src, const int* __restrict__ rs,
    const ushort* __restrict__ hs2b, const float* __restrict__ as2,
    const float* __restrict__ ad2, const float* __restrict__ b2,
    float* __restrict__ out, int n) {
    int gid = blockIdx.x * blockDim.x + threadIdx.x;
    int node = gid >> 6;
    int lane = threadIdx.x & 63;
    if (node >= n) return;
    int g = lane >> 3, l = lane & 7;
    float ad_v = ad2[node];
    int start = rs[node], cnt = rs[node + 1] - start;
    float a0 = 0.f, a1 = 0.f, a2 = 0.f, a3 = 0.f, dacc = 0.f;
    for (int i = g; i < cnt; i += 8) {
        int s = csr_src[start + i];
        float t = as2[s] + ad_v;
        t = (t >= 0.f) ? t : NEG_SLOPE * t;
        float w = __expf(t);
        uint2 v = *(const uint2*)(hs2b + (size_t)s * 32 + l * 4);
        a0 += bf2f(v.x & 0xffffu) * w;
        a1 += bf2f(v.x >> 16) * w;
        a2 += bf2f(v.y & 0xffffu) * w;
        a3 += bf2f(v.y >> 16) * w;
        dacc += w;
    }
#pragma unroll
    for (int m = 8; m <= 32; m <<= 1) {
        a0 += __shfl_xor(a0, m, 64);
        a1 += __shfl_xor(a1, m, 64);
        a2 += __shfl_xor(a2, m, 64);
        a3 += __shfl_xor(a3, m, 64);
        dacc += __shfl_xor(dacc, m, 64);
    }
    if (g == 0) {
        float inv = 1.f / (dacc + 1e-16f);
        float4 bv = ((const float4*)b2)[l];
        float4 o;
        o.x = fmaf(a0, inv, bv.x);
        o.y = fmaf(a1, inv, bv.y);
        o.z = fmaf(a2, inv, bv.z);
        o.w = fmaf(a3, inv, bv.w);
        *(float4*)(out + (size_t)node * 32 + l * 4) = o;
    }
}

extern "C" void kernel_launch(void* const* d_in, const int* in_sizes, int n_in,
                              void* d_out, int out_size, void* d_ws, size_t ws_size,
                              hipStream_t stream) {
    const float* x      = (const float*)d_in[0];
    const int*   eidx   = (const int*)d_in[1];
    const float* W1_src = (const float*)d_in[2];
    const float* W1_dst = (const float*)d_in[3];
    const float* a1_src = (const float*)d_in[4];
    const float* a1_dst = (const float*)d_in[5];
    const float* b1     = (const float*)d_in[6];
    const float* W2_src = (const float*)d_in[7];
    const float* W2_dst = (const float*)d_in[8];
    const float* a2_src = (const float*)d_in[9];
    const float* a2_dst = (const float*)d_in[10];
    const float* b2     = (const float*)d_in[11];

    const int n = in_sizes[0] / 128;    // 50000
    const int E = in_sizes[1] / 2;      // 800000
    const int* srcp = eidx;
    const int* dstp = eidx + E;
    const int nb = (n + 255) / 256;     // 196 chunks

    char* ws = (char*)d_ws;
    size_t o = 0;
    auto alloc = [&](size_t bytes) {
        void* p = ws + o;
        o += (bytes + 255) & ~(size_t)255;
        return p;
    };
    ushort* W1t  = (ushort*)alloc(256 * 128 * 2);
    ushort* W2t  = (ushort*)alloc(32 * 256 * 2);
    ushort* hs1b = (ushort*)alloc((size_t)n * 256 * 2);
    ushort* h1b  = (ushort*)alloc((size_t)n * 256 * 2);
    ushort* hs2b = (ushort*)alloc((size_t)n * 32 * 2);
    float* as1 = (float*)alloc((size_t)n * 8 * 4);
    float* ad1 = (float*)alloc((size_t)n * 8 * 4);
    float* as2 = (float*)alloc((size_t)n * 4);
    float* ad2 = (float*)alloc((size_t)n * 4);
    float* wc1 = (float*)alloc(1024 * 4);
    float* wc2 = (float*)alloc(256 * 4);
    int* deg     = (int*)alloc((size_t)n * 4);
    int* rs      = (int*)alloc(((size_t)n + 1) * 4);
    int* cursor  = (int*)alloc((size_t)n * 4);
    int* bsum    = (int*)alloc(256 * 4);
    int* csr_src = (int*)alloc((size_t)E * 4);

    hipMemsetAsync(deg, 0, (size_t)n * sizeof(int), stream);

    // CSR build
    hist_kernel<<<(E + 255) / 256, 256, 0, stream>>>(dstp, deg, E);
    scan_block<<<nb, 256, 0, stream>>>(deg, rs, bsum, n);
    rs_kernel<<<nb, 256, 0, stream>>>(deg, bsum, rs, cursor, n, E, nb);
    fill_kernel<<<(E + 255) / 256, 256, 0, stream>>>(srcp, dstp, cursor,
                                                     csr_src, E);

    prep_weights<<<(32768 + 8192 + 1024 + 256 + 255) / 256, 256, 0, stream>>>(
        W1_src, W2_src, W1_dst, a1_dst, W2_dst, a2_dst, W1t, W2t, wc1, wc2);

    // layer 1
    gemm1_mfma<<<((n + 127) / 128) * 2, 256, 0, stream>>>(
        x, W1t, a1_src, wc1, hs1b, as1, ad1, n);
    gather1<<<(n + 3) / 4, 256, 0, stream>>>(
        csr_src, rs, hs1b, as1, ad1, b1, h1b, n);

    // layer 2
    gemm2_mfma<<<(n + 127) / 128, 256, 0, stream>>>(
        h1b, W2t, a2_src, wc2, hs2b, as2, ad2, n);
    gather2<<<(n + 3) / 4, 256, 0, stream>>>(
        csr_src, rs, hs2b, as2, ad2, b2, (float*)d_out, n);
}